// Round 3
// baseline (729.058 us; speedup 1.0000x reference)
//
#include <hip/hip_runtime.h>
#include <hip/hip_bf16.h>

// GraphSAGE 3-layer: 40 -> 64 -> 128 -> 3, mean aggregation over fixed edges.
// R3: k_lin was latency-bound (VALUBusy 40%, occ 36%, 2 blocks/CU). Now:
// 8 nodes/wave, fully-unrolled f-loop (const-offset loads), 1042 blocks.

static constexpr int NN = 100000;
static constexpr int EE = 1600000;
static constexpr int NB = (NN + 255) / 256;   // 391 scan blocks

// ---------------- degree histogram ----------------
__global__ __launch_bounds__(256) void k_deg(const int* __restrict__ dst, int* __restrict__ deg) {
    int e = blockIdx.x * 256 + threadIdx.x;
    if (e < EE) atomicAdd(&deg[dst[e]], 1);
}

// ---------------- hierarchical scan: block sums ----------------
__global__ __launch_bounds__(256) void k_bsum(const int* __restrict__ deg, int* __restrict__ bsum) {
    int i = blockIdx.x * 256 + threadIdx.x;
    int v = (i < NN) ? deg[i] : 0;
    int lane = threadIdx.x & 63, wid = threadIdx.x >> 6;
#pragma unroll
    for (int d = 32; d; d >>= 1) v += __shfl_down(v, d, 64);
    __shared__ int wsum[4];
    if (lane == 0) wsum[wid] = v;
    __syncthreads();
    if (threadIdx.x == 0) bsum[blockIdx.x] = wsum[0] + wsum[1] + wsum[2] + wsum[3];
}

// ---------------- scan of 391 block sums (one block) ----------------
__global__ __launch_bounds__(512) void k_bscan(const int* __restrict__ bsum, int* __restrict__ boff,
                                               int* __restrict__ row_start) {
    __shared__ int s[512];
    int tid = threadIdx.x;
    int v = (tid < NB) ? bsum[tid] : 0;
    s[tid] = v;
    __syncthreads();
    for (int d = 1; d < 512; d <<= 1) {
        int t = (tid >= d) ? s[tid - d] : 0;
        __syncthreads();
        s[tid] += t;
        __syncthreads();
    }
    if (tid < NB) boff[tid] = s[tid] - v;   // exclusive
    if (tid == 0) row_start[NN] = EE;
}

// ---------------- final scan: row_start + deg_inv ----------------
__global__ __launch_bounds__(256) void k_scan2(const int* __restrict__ deg, const int* __restrict__ boff,
                                               int* __restrict__ row_start, float* __restrict__ deg_inv) {
    int tid = threadIdx.x, lane = tid & 63, wid = tid >> 6;
    int i = blockIdx.x * 256 + tid;
    int v = (i < NN) ? deg[i] : 0;
    int inc = v;
#pragma unroll
    for (int d = 1; d < 64; d <<= 1) {
        int t = __shfl_up(inc, d, 64);
        if (lane >= d) inc += t;
    }
    __shared__ int wsum[4];
    if (lane == 63) wsum[wid] = inc;
    __syncthreads();
    if (tid == 0) {
        int s = 0;
#pragma unroll
        for (int j = 0; j < 4; ++j) { int t = wsum[j]; wsum[j] = s; s += t; }
    }
    __syncthreads();
    if (i < NN) {
        row_start[i] = boff[blockIdx.x] + wsum[wid] + (inc - v);
        deg_inv[i] = (v > 0) ? 1.0f / (float)v : 0.0f;
    }
}

// ---------------- CSR scatter ----------------
__global__ __launch_bounds__(256) void k_fill(const int* __restrict__ src, const int* __restrict__ dst,
                                              const int* __restrict__ row_start, int* __restrict__ cursor,
                                              int* __restrict__ csr_src) {
    int e = blockIdx.x * 256 + threadIdx.x;
    if (e < EE) {
        int d = dst[e];
        int pos = atomicAdd(&cursor[d], 1);
        csr_src[row_start[d] + pos] = src[e];
    }
}

// ---------------- mean aggregation: 16 lanes/node, float4/lane ----------------
template<int F>
__global__ __launch_bounds__(256) void k_mean4(const float* __restrict__ xin,
                                               const int* __restrict__ row_start,
                                               const int* __restrict__ csr_src,
                                               const float* __restrict__ deg_inv,
                                               float* __restrict__ mean) {
    int gid = blockIdx.x * 256 + threadIdx.x;
    int node = gid >> 4;
    int fq = (gid & 15) * 4;
    if (node >= NN) return;
    if (fq >= F) return;                     // F=40: lanes 10..15 of group idle
    int rs = row_start[node], re = row_start[node + 1];
    float a0x = 0, a0y = 0, a0z = 0, a0w = 0;
    float a1x = 0, a1y = 0, a1z = 0, a1w = 0;
    float a2x = 0, a2y = 0, a2z = 0, a2w = 0;
    float a3x = 0, a3y = 0, a3z = 0, a3w = 0;
    int k = rs;
    for (; k + 4 <= re; k += 4) {
        int s0 = csr_src[k], s1 = csr_src[k + 1], s2 = csr_src[k + 2], s3 = csr_src[k + 3];
        float4 v0 = *(const float4*)&xin[(size_t)s0 * F + fq];
        float4 v1 = *(const float4*)&xin[(size_t)s1 * F + fq];
        float4 v2 = *(const float4*)&xin[(size_t)s2 * F + fq];
        float4 v3 = *(const float4*)&xin[(size_t)s3 * F + fq];
        a0x += v0.x; a0y += v0.y; a0z += v0.z; a0w += v0.w;
        a1x += v1.x; a1y += v1.y; a1z += v1.z; a1w += v1.w;
        a2x += v2.x; a2y += v2.y; a2z += v2.z; a2w += v2.w;
        a3x += v3.x; a3y += v3.y; a3z += v3.z; a3w += v3.w;
    }
    for (; k < re; ++k) {
        float4 v0 = *(const float4*)&xin[(size_t)csr_src[k] * F + fq];
        a0x += v0.x; a0y += v0.y; a0z += v0.z; a0w += v0.w;
    }
    float di = deg_inv[node];
    float4 m;
    m.x = (a0x + a1x + a2x + a3x) * di;
    m.y = (a0y + a1y + a2y + a3y) * di;
    m.z = (a0z + a1z + a2z + a3z) * di;
    m.w = (a0w + a1w + a2w + a3w) * di;
    *(float4*)&mean[(size_t)node * F + fq] = m;
}

// ---------------- linear: out[n, obase+lane] = mean@Wl.T + b + root@Wr.T ----------------
// 64 outputs per block-column (blockIdx.y picks which 64 of FoutT). Weights
// transposed in LDS, pitch 65 (conflict-free stage, 2-way-free read).
// 8 nodes per wave, f-loop fully unrolled -> const-offset loads.
template<int Fin, int FoutT, bool RELU>
__global__ __launch_bounds__(256) void k_lin8(
    const float* __restrict__ mean, const float* __restrict__ root,
    const float* __restrict__ Wl, const float* __restrict__ bias, const float* __restrict__ Wr,
    float* __restrict__ out) {
    __shared__ float sWl[Fin * 65];
    __shared__ float sWr[Fin * 65];
    const int obase = blockIdx.y * 64;
    for (int idx = threadIdx.x; idx < Fin * 64; idx += 256) {
        int o = idx / Fin, f = idx % Fin;                 // coalesced global read
        sWl[f * 65 + o] = Wl[(size_t)obase * Fin + idx];  // stride-65 write: no conflict
        sWr[f * 65 + o] = Wr[(size_t)obase * Fin + idx];
    }
    __syncthreads();
    const int lane = threadIdx.x & 63;
    const int wid = threadIdx.x >> 6;
    const float bo = bias[obase + lane];
    const int groups = NN / 8;                            // 12500
    for (int g = blockIdx.x * 4 + wid; g < groups; g += gridDim.x * 4) {
        const float* pm = mean + (size_t)g * 8 * Fin;
        const float* pr = root + (size_t)g * 8 * Fin;
        float acc[8];
#pragma unroll
        for (int j = 0; j < 8; ++j) acc[j] = bo;
#pragma unroll
        for (int f = 0; f < Fin; f += 4) {
            float4 m[8], r[8];
#pragma unroll
            for (int j = 0; j < 8; ++j) {
                m[j] = *(const float4*)(pm + j * Fin + f);   // const offsets
                r[j] = *(const float4*)(pr + j * Fin + f);
            }
#pragma unroll
            for (int ff = 0; ff < 4; ++ff) {
                float wl = sWl[(f + ff) * 65 + lane];
                float wr = sWr[(f + ff) * 65 + lane];
#pragma unroll
                for (int j = 0; j < 8; ++j) {
                    const float* mj = (const float*)&m[j];
                    const float* rj = (const float*)&r[j];
                    acc[j] += mj[ff] * wl + rj[ff] * wr;
                }
            }
        }
        float* po = out + (size_t)g * 8 * FoutT + obase + lane;
#pragma unroll
        for (int j = 0; j < 8; ++j) {
            float v = acc[j];
            if (RELU) v = fmaxf(v, 0.f);
            po[j * FoutT] = v;
        }
    }
}

// ---------------- layer 3 transforms: z = h2@W4l.T, r = h2@W4r.T (no bias) ----------------
__global__ __launch_bounds__(256) void k_zr(const float* __restrict__ h2,
                                            const float* __restrict__ W4l, const float* __restrict__ W4r,
                                            float* __restrict__ z, float* __restrict__ r) {
    int node = (blockIdx.x * 256 + threadIdx.x) >> 6;
    int lane = threadIdx.x & 63;
    if (node >= NN) return;
    float h0 = h2[(size_t)node * 128 + lane];
    float h1v = h2[(size_t)node * 128 + 64 + lane];
    float zc0 = h0 * W4l[0 * 128 + lane] + h1v * W4l[0 * 128 + 64 + lane];
    float zc1 = h0 * W4l[1 * 128 + lane] + h1v * W4l[1 * 128 + 64 + lane];
    float zc2 = h0 * W4l[2 * 128 + lane] + h1v * W4l[2 * 128 + 64 + lane];
    float rc0 = h0 * W4r[0 * 128 + lane] + h1v * W4r[0 * 128 + 64 + lane];
    float rc1 = h0 * W4r[1 * 128 + lane] + h1v * W4r[1 * 128 + 64 + lane];
    float rc2 = h0 * W4r[2 * 128 + lane] + h1v * W4r[2 * 128 + 64 + lane];
#pragma unroll
    for (int d = 32; d; d >>= 1) {
        zc0 += __shfl_down(zc0, d, 64); zc1 += __shfl_down(zc1, d, 64); zc2 += __shfl_down(zc2, d, 64);
        rc0 += __shfl_down(rc0, d, 64); rc1 += __shfl_down(rc1, d, 64); rc2 += __shfl_down(rc2, d, 64);
    }
    if (lane == 0) {
        z[(size_t)node * 3 + 0] = zc0; z[(size_t)node * 3 + 1] = zc1; z[(size_t)node * 3 + 2] = zc2;
        r[(size_t)node * 3 + 0] = rc0; r[(size_t)node * 3 + 1] = rc1; r[(size_t)node * 3 + 2] = rc2;
    }
}

// ---------------- final: out = mean(z)[n] + r[n] + b4 ----------------
__global__ __launch_bounds__(256) void k_final(const float* __restrict__ z, const float* __restrict__ r,
                                               const float* __restrict__ b4,
                                               const int* __restrict__ row_start, const int* __restrict__ csr_src,
                                               const float* __restrict__ deg_inv, float* __restrict__ out) {
    int n = blockIdx.x * 256 + threadIdx.x;
    if (n >= NN) return;
    int rs = row_start[n], re = row_start[n + 1];
    float a0 = 0, a1 = 0, a2 = 0, b0 = 0, b1 = 0, b2 = 0;
    int k = rs;
    for (; k + 2 <= re; k += 2) {
        int s0 = csr_src[k], s1 = csr_src[k + 1];
        a0 += z[3 * (size_t)s0 + 0]; a1 += z[3 * (size_t)s0 + 1]; a2 += z[3 * (size_t)s0 + 2];
        b0 += z[3 * (size_t)s1 + 0]; b1 += z[3 * (size_t)s1 + 1]; b2 += z[3 * (size_t)s1 + 2];
    }
    if (k < re) {
        int s0 = csr_src[k];
        a0 += z[3 * (size_t)s0 + 0]; a1 += z[3 * (size_t)s0 + 1]; a2 += z[3 * (size_t)s0 + 2];
    }
    float di = deg_inv[n];
    out[(size_t)n * 3 + 0] = (a0 + b0) * di + r[(size_t)n * 3 + 0] + b4[0];
    out[(size_t)n * 3 + 1] = (a1 + b1) * di + r[(size_t)n * 3 + 1] + b4[1];
    out[(size_t)n * 3 + 2] = (a2 + b2) * di + r[(size_t)n * 3 + 2] + b4[2];
}

extern "C" void kernel_launch(void* const* d_in, const int* in_sizes, int n_in,
                              void* d_out, int out_size, void* d_ws, size_t ws_size,
                              hipStream_t stream) {
    const float* x   = (const float*)d_in[0];
    const int*   ei  = (const int*)d_in[1];
    const float* W1l = (const float*)d_in[2];
    const float* b1  = (const float*)d_in[3];
    const float* W1r = (const float*)d_in[4];
    const float* W2l = (const float*)d_in[5];
    const float* b2  = (const float*)d_in[6];
    const float* W2r = (const float*)d_in[7];
    const float* W4l = (const float*)d_in[8];
    const float* b4  = (const float*)d_in[9];
    const float* W4r = (const float*)d_in[10];
    float* out = (float*)d_out;

    char* ws = (char*)d_ws;
    size_t off = 0;
    auto alloc = [&](size_t bytes) -> void* {
        void* p = ws + off;
        off = (off + bytes + 255) & ~(size_t)255;
        return p;
    };
    int*   deg       = (int*)alloc((size_t)NN * 4);
    int*   row_start = (int*)alloc(((size_t)NN + 1) * 4);
    int*   cursor    = (int*)alloc((size_t)NN * 4);
    int*   csr_src   = (int*)alloc((size_t)EE * 4);
    float* deg_inv   = (float*)alloc((size_t)NN * 4);
    int*   bsum      = (int*)alloc((size_t)NB * 4);
    int*   boff      = (int*)alloc((size_t)NB * 4);
    float* h1        = (float*)alloc((size_t)NN * 64 * 4);
    float* h2        = (float*)alloc((size_t)NN * 128 * 4);
    float* scratch   = (float*)alloc((size_t)NN * 64 * 4);  // mean1 / mean2 / z+r (reused)
    float* mean1 = scratch;                 // N x 40
    float* mean2 = scratch;                 // N x 64  (after mean1 dead)
    float* zbuf  = scratch;                 // N x 3   (after mean2 dead)
    float* rbuf  = scratch + (size_t)NN * 3;

    const int* e_src = ei;
    const int* e_dst = ei + EE;

    hipMemsetAsync(deg, 0, (size_t)NN * 4, stream);
    hipMemsetAsync(cursor, 0, (size_t)NN * 4, stream);

    k_deg<<<(EE + 255) / 256, 256, 0, stream>>>(e_dst, deg);
    k_bsum<<<NB, 256, 0, stream>>>(deg, bsum);
    k_bscan<<<1, 512, 0, stream>>>(bsum, boff, row_start);
    k_scan2<<<NB, 256, 0, stream>>>(deg, boff, row_start, deg_inv);
    k_fill<<<(EE + 255) / 256, 256, 0, stream>>>(e_src, e_dst, row_start, cursor, csr_src);

    const int mean_blocks = ((size_t)NN * 16 + 255) / 256;   // 6250
    const int lin_blocks = 1042;   // 12500 groups / (1042*4 waves) = 3 groups/wave exactly

    // layer 1: 40 -> 64
    k_mean4<40><<<mean_blocks, 256, 0, stream>>>(x, row_start, csr_src, deg_inv, mean1);
    k_lin8<40, 64, true><<<dim3(lin_blocks, 1), 256, 0, stream>>>(mean1, x, W1l, b1, W1r, h1);

    // layer 2: 64 -> 128
    k_mean4<64><<<mean_blocks, 256, 0, stream>>>(h1, row_start, csr_src, deg_inv, mean2);
    k_lin8<64, 128, true><<<dim3(lin_blocks, 2), 256, 0, stream>>>(mean2, h1, W2l, b2, W2r, h2);

    // layer 3: 128 -> 3, transform-before-gather
    k_zr<<<((size_t)NN * 64 + 255) / 256, 256, 0, stream>>>(h2, W4l, W4r, zbuf, rbuf);
    k_final<<<(NN + 255) / 256, 256, 0, stream>>>(zbuf, rbuf, b4, row_start, csr_src, deg_inv, out);
}

// Round 4
// 697.582 us; speedup vs baseline: 1.0451x; 1.0451x over previous
//
#include <hip/hip_runtime.h>
#include <hip/hip_bf16.h>

// GraphSAGE 3-layer: 40 -> 64 -> 128 -> 3, mean aggregation over fixed edges.
// R4: revert k_lin to NPW=4/rolled (R3's NPW=8 unroll hit VGPR=140, occ 10.5%);
// raise grids to LDS-cap residency. k_mean: 8-deep edge unroll + exact 10-lane
// mapping for F=40. Layer-3 z/r padded to float4 for 1-load-per-edge gather.

static constexpr int NN = 100000;
static constexpr int EE = 1600000;
static constexpr int NB = (NN + 255) / 256;   // 391 scan blocks

// ---------------- degree histogram ----------------
__global__ __launch_bounds__(256) void k_deg(const int* __restrict__ dst, int* __restrict__ deg) {
    int e = blockIdx.x * 256 + threadIdx.x;
    if (e < EE) atomicAdd(&deg[dst[e]], 1);
}

// ---------------- hierarchical scan: block sums ----------------
__global__ __launch_bounds__(256) void k_bsum(const int* __restrict__ deg, int* __restrict__ bsum) {
    int i = blockIdx.x * 256 + threadIdx.x;
    int v = (i < NN) ? deg[i] : 0;
    int lane = threadIdx.x & 63, wid = threadIdx.x >> 6;
#pragma unroll
    for (int d = 32; d; d >>= 1) v += __shfl_down(v, d, 64);
    __shared__ int wsum[4];
    if (lane == 0) wsum[wid] = v;
    __syncthreads();
    if (threadIdx.x == 0) bsum[blockIdx.x] = wsum[0] + wsum[1] + wsum[2] + wsum[3];
}

// ---------------- scan of 391 block sums (one block) ----------------
__global__ __launch_bounds__(512) void k_bscan(const int* __restrict__ bsum, int* __restrict__ boff,
                                               int* __restrict__ row_start) {
    __shared__ int s[512];
    int tid = threadIdx.x;
    int v = (tid < NB) ? bsum[tid] : 0;
    s[tid] = v;
    __syncthreads();
    for (int d = 1; d < 512; d <<= 1) {
        int t = (tid >= d) ? s[tid - d] : 0;
        __syncthreads();
        s[tid] += t;
        __syncthreads();
    }
    if (tid < NB) boff[tid] = s[tid] - v;   // exclusive
    if (tid == 0) row_start[NN] = EE;
}

// ---------------- final scan: row_start + deg_inv ----------------
__global__ __launch_bounds__(256) void k_scan2(const int* __restrict__ deg, const int* __restrict__ boff,
                                               int* __restrict__ row_start, float* __restrict__ deg_inv) {
    int tid = threadIdx.x, lane = tid & 63, wid = tid >> 6;
    int i = blockIdx.x * 256 + tid;
    int v = (i < NN) ? deg[i] : 0;
    int inc = v;
#pragma unroll
    for (int d = 1; d < 64; d <<= 1) {
        int t = __shfl_up(inc, d, 64);
        if (lane >= d) inc += t;
    }
    __shared__ int wsum[4];
    if (lane == 63) wsum[wid] = inc;
    __syncthreads();
    if (tid == 0) {
        int s = 0;
#pragma unroll
        for (int j = 0; j < 4; ++j) { int t = wsum[j]; wsum[j] = s; s += t; }
    }
    __syncthreads();
    if (i < NN) {
        row_start[i] = boff[blockIdx.x] + wsum[wid] + (inc - v);
        deg_inv[i] = (v > 0) ? 1.0f / (float)v : 0.0f;
    }
}

// ---------------- CSR scatter ----------------
__global__ __launch_bounds__(256) void k_fill(const int* __restrict__ src, const int* __restrict__ dst,
                                              const int* __restrict__ row_start, int* __restrict__ cursor,
                                              int* __restrict__ csr_src) {
    int e = blockIdx.x * 256 + threadIdx.x;
    if (e < EE) {
        int d = dst[e];
        int pos = atomicAdd(&cursor[d], 1);
        csr_src[row_start[d] + pos] = src[e];
    }
}

// ---------------- mean aggregation: LPN lanes/node, float4/lane, 8-deep unroll ----------------
template<int F, int LPN>
__global__ __launch_bounds__(256) void k_mean8(const float* __restrict__ xin,
                                               const int* __restrict__ row_start,
                                               const int* __restrict__ csr_src,
                                               const float* __restrict__ deg_inv,
                                               float* __restrict__ mean) {
    int gid = blockIdx.x * 256 + threadIdx.x;
    int node = gid / LPN;                    // compiler emits magic-mul for const LPN
    int fq = (gid % LPN) * 4;
    if (node >= NN) return;
    int rs = row_start[node], re = row_start[node + 1];
    const float* xq = xin + fq;
    float a0x = 0, a0y = 0, a0z = 0, a0w = 0;
    float a1x = 0, a1y = 0, a1z = 0, a1w = 0;
    float a2x = 0, a2y = 0, a2z = 0, a2w = 0;
    float a3x = 0, a3y = 0, a3z = 0, a3w = 0;
    int k = rs;
    for (; k + 8 <= re; k += 8) {
        int s0 = csr_src[k + 0], s1 = csr_src[k + 1], s2 = csr_src[k + 2], s3 = csr_src[k + 3];
        int s4 = csr_src[k + 4], s5 = csr_src[k + 5], s6 = csr_src[k + 6], s7 = csr_src[k + 7];
        float4 v0 = *(const float4*)(xq + (size_t)s0 * F);
        float4 v1 = *(const float4*)(xq + (size_t)s1 * F);
        float4 v2 = *(const float4*)(xq + (size_t)s2 * F);
        float4 v3 = *(const float4*)(xq + (size_t)s3 * F);
        float4 v4 = *(const float4*)(xq + (size_t)s4 * F);
        float4 v5 = *(const float4*)(xq + (size_t)s5 * F);
        float4 v6 = *(const float4*)(xq + (size_t)s6 * F);
        float4 v7 = *(const float4*)(xq + (size_t)s7 * F);
        a0x += v0.x; a0y += v0.y; a0z += v0.z; a0w += v0.w;
        a1x += v1.x; a1y += v1.y; a1z += v1.z; a1w += v1.w;
        a2x += v2.x; a2y += v2.y; a2z += v2.z; a2w += v2.w;
        a3x += v3.x; a3y += v3.y; a3z += v3.z; a3w += v3.w;
        a0x += v4.x; a0y += v4.y; a0z += v4.z; a0w += v4.w;
        a1x += v5.x; a1y += v5.y; a1z += v5.z; a1w += v5.w;
        a2x += v6.x; a2y += v6.y; a2z += v6.z; a2w += v6.w;
        a3x += v7.x; a3y += v7.y; a3z += v7.z; a3w += v7.w;
    }
    for (; k + 2 <= re; k += 2) {
        int s0 = csr_src[k + 0], s1 = csr_src[k + 1];
        float4 v0 = *(const float4*)(xq + (size_t)s0 * F);
        float4 v1 = *(const float4*)(xq + (size_t)s1 * F);
        a0x += v0.x; a0y += v0.y; a0z += v0.z; a0w += v0.w;
        a1x += v1.x; a1y += v1.y; a1z += v1.z; a1w += v1.w;
    }
    if (k < re) {
        float4 v0 = *(const float4*)(xq + (size_t)csr_src[k] * F);
        a0x += v0.x; a0y += v0.y; a0z += v0.z; a0w += v0.w;
    }
    float di = deg_inv[node];
    float4 m;
    m.x = (a0x + a1x + a2x + a3x) * di;
    m.y = (a0y + a1y + a2y + a3y) * di;
    m.z = (a0z + a1z + a2z + a3z) * di;
    m.w = (a0w + a1w + a2w + a3w) * di;
    *(float4*)&mean[(size_t)node * F + fq] = m;
}

// ---------------- linear: out[n, obase+lane] = mean@Wl.T + b + root@Wr.T ----------------
// 64 outputs per block-column (blockIdx.y picks which 64 of FoutT). Weights
// transposed in LDS, pitch 65 (conflict-free stage + read). 4 nodes/wave,
// rolled f-loop (R2 shape: VGPR ~56). Grid sized for LDS-cap residency.
template<int Fin, int FoutT, bool RELU>
__global__ __launch_bounds__(256) void k_lin4(
    const float* __restrict__ mean, const float* __restrict__ root,
    const float* __restrict__ Wl, const float* __restrict__ bias, const float* __restrict__ Wr,
    float* __restrict__ out) {
    __shared__ float sWl[Fin * 65];
    __shared__ float sWr[Fin * 65];
    const int obase = blockIdx.y * 64;
    for (int idx = threadIdx.x; idx < Fin * 64; idx += 256) {
        int o = idx / Fin, f = idx % Fin;                 // coalesced global read
        sWl[f * 65 + o] = Wl[(size_t)obase * Fin + idx];  // stride-65 write: no conflict
        sWr[f * 65 + o] = Wr[(size_t)obase * Fin + idx];
    }
    __syncthreads();
    const int lane = threadIdx.x & 63;
    const int wid = threadIdx.x >> 6;
    const float bo = bias[obase + lane];
    const int groups = NN / 4;                            // 25000
    for (int g = blockIdx.x * 4 + wid; g < groups; g += gridDim.x * 4) {
        int n0 = g * 4;
        float acc0 = bo, acc1 = bo, acc2 = bo, acc3 = bo;
        for (int f = 0; f < Fin; f += 4) {
            float4 m0 = *(const float4*)&mean[(size_t)(n0 + 0) * Fin + f];
            float4 m1 = *(const float4*)&mean[(size_t)(n0 + 1) * Fin + f];
            float4 m2 = *(const float4*)&mean[(size_t)(n0 + 2) * Fin + f];
            float4 m3 = *(const float4*)&mean[(size_t)(n0 + 3) * Fin + f];
            float4 r0 = *(const float4*)&root[(size_t)(n0 + 0) * Fin + f];
            float4 r1 = *(const float4*)&root[(size_t)(n0 + 1) * Fin + f];
            float4 r2 = *(const float4*)&root[(size_t)(n0 + 2) * Fin + f];
            float4 r3 = *(const float4*)&root[(size_t)(n0 + 3) * Fin + f];
#define SAGE_STEP(FF, C) { \
            float wl = sWl[(f + FF) * 65 + lane]; \
            float wr = sWr[(f + FF) * 65 + lane]; \
            acc0 += m0.C * wl + r0.C * wr; \
            acc1 += m1.C * wl + r1.C * wr; \
            acc2 += m2.C * wl + r2.C * wr; \
            acc3 += m3.C * wl + r3.C * wr; }
            SAGE_STEP(0, x) SAGE_STEP(1, y) SAGE_STEP(2, z) SAGE_STEP(3, w)
#undef SAGE_STEP
        }
        if (RELU) {
            acc0 = fmaxf(acc0, 0.f); acc1 = fmaxf(acc1, 0.f);
            acc2 = fmaxf(acc2, 0.f); acc3 = fmaxf(acc3, 0.f);
        }
        out[(size_t)(n0 + 0) * FoutT + obase + lane] = acc0;
        out[(size_t)(n0 + 1) * FoutT + obase + lane] = acc1;
        out[(size_t)(n0 + 2) * FoutT + obase + lane] = acc2;
        out[(size_t)(n0 + 3) * FoutT + obase + lane] = acc3;
    }
}

// ---------------- layer 3 transforms: z = h2@W4l.T, r = h2@W4r.T (padded float4 rows) ----------------
__global__ __launch_bounds__(256) void k_zr(const float* __restrict__ h2,
                                            const float* __restrict__ W4l, const float* __restrict__ W4r,
                                            float* __restrict__ z, float* __restrict__ r) {
    int node = (blockIdx.x * 256 + threadIdx.x) >> 6;
    int lane = threadIdx.x & 63;
    if (node >= NN) return;
    float h0 = h2[(size_t)node * 128 + lane];
    float h1v = h2[(size_t)node * 128 + 64 + lane];
    float zc0 = h0 * W4l[0 * 128 + lane] + h1v * W4l[0 * 128 + 64 + lane];
    float zc1 = h0 * W4l[1 * 128 + lane] + h1v * W4l[1 * 128 + 64 + lane];
    float zc2 = h0 * W4l[2 * 128 + lane] + h1v * W4l[2 * 128 + 64 + lane];
    float rc0 = h0 * W4r[0 * 128 + lane] + h1v * W4r[0 * 128 + 64 + lane];
    float rc1 = h0 * W4r[1 * 128 + lane] + h1v * W4r[1 * 128 + 64 + lane];
    float rc2 = h0 * W4r[2 * 128 + lane] + h1v * W4r[2 * 128 + 64 + lane];
#pragma unroll
    for (int d = 32; d; d >>= 1) {
        zc0 += __shfl_down(zc0, d, 64); zc1 += __shfl_down(zc1, d, 64); zc2 += __shfl_down(zc2, d, 64);
        rc0 += __shfl_down(rc0, d, 64); rc1 += __shfl_down(rc1, d, 64); rc2 += __shfl_down(rc2, d, 64);
    }
    if (lane == 0) {
        *(float4*)&z[(size_t)node * 4] = make_float4(zc0, zc1, zc2, 0.f);
        *(float4*)&r[(size_t)node * 4] = make_float4(rc0, rc1, rc2, 0.f);
    }
}

// ---------------- final: out = mean(z)[n] + r[n] + b4 ----------------
__global__ __launch_bounds__(256) void k_final(const float* __restrict__ z, const float* __restrict__ r,
                                               const float* __restrict__ b4,
                                               const int* __restrict__ row_start, const int* __restrict__ csr_src,
                                               const float* __restrict__ deg_inv, float* __restrict__ out) {
    int n = blockIdx.x * 256 + threadIdx.x;
    if (n >= NN) return;
    int rs = row_start[n], re = row_start[n + 1];
    float a0 = 0, a1 = 0, a2 = 0, b0 = 0, b1 = 0, b2 = 0;
    int k = rs;
    for (; k + 4 <= re; k += 4) {
        int s0 = csr_src[k], s1 = csr_src[k + 1], s2 = csr_src[k + 2], s3 = csr_src[k + 3];
        float4 z0 = *(const float4*)&z[4 * (size_t)s0];
        float4 z1 = *(const float4*)&z[4 * (size_t)s1];
        float4 z2 = *(const float4*)&z[4 * (size_t)s2];
        float4 z3 = *(const float4*)&z[4 * (size_t)s3];
        a0 += z0.x; a1 += z0.y; a2 += z0.z;
        b0 += z1.x; b1 += z1.y; b2 += z1.z;
        a0 += z2.x; a1 += z2.y; a2 += z2.z;
        b0 += z3.x; b1 += z3.y; b2 += z3.z;
    }
    for (; k < re; ++k) {
        float4 z0 = *(const float4*)&z[4 * (size_t)csr_src[k]];
        a0 += z0.x; a1 += z0.y; a2 += z0.z;
    }
    float di = deg_inv[n];
    float4 rn = *(const float4*)&r[4 * (size_t)n];
    out[(size_t)n * 3 + 0] = (a0 + b0) * di + rn.x + b4[0];
    out[(size_t)n * 3 + 1] = (a1 + b1) * di + rn.y + b4[1];
    out[(size_t)n * 3 + 2] = (a2 + b2) * di + rn.z + b4[2];
}

extern "C" void kernel_launch(void* const* d_in, const int* in_sizes, int n_in,
                              void* d_out, int out_size, void* d_ws, size_t ws_size,
                              hipStream_t stream) {
    const float* x   = (const float*)d_in[0];
    const int*   ei  = (const int*)d_in[1];
    const float* W1l = (const float*)d_in[2];
    const float* b1  = (const float*)d_in[3];
    const float* W1r = (const float*)d_in[4];
    const float* W2l = (const float*)d_in[5];
    const float* b2  = (const float*)d_in[6];
    const float* W2r = (const float*)d_in[7];
    const float* W4l = (const float*)d_in[8];
    const float* b4  = (const float*)d_in[9];
    const float* W4r = (const float*)d_in[10];
    float* out = (float*)d_out;

    char* ws = (char*)d_ws;
    size_t off = 0;
    auto alloc = [&](size_t bytes) -> void* {
        void* p = ws + off;
        off = (off + bytes + 255) & ~(size_t)255;
        return p;
    };
    int*   deg       = (int*)alloc((size_t)NN * 4);
    int*   row_start = (int*)alloc(((size_t)NN + 1) * 4);
    int*   cursor    = (int*)alloc((size_t)NN * 4);
    int*   csr_src   = (int*)alloc((size_t)EE * 4);
    float* deg_inv   = (float*)alloc((size_t)NN * 4);
    int*   bsum      = (int*)alloc((size_t)NB * 4);
    int*   boff      = (int*)alloc((size_t)NB * 4);
    float* h1        = (float*)alloc((size_t)NN * 64 * 4);
    float* h2        = (float*)alloc((size_t)NN * 128 * 4);
    float* scratch   = (float*)alloc((size_t)NN * 64 * 4);  // mean1 / mean2 / z+r (reused)
    float* mean1 = scratch;                 // N x 40
    float* mean2 = scratch;                 // N x 64  (after mean1 dead)
    float* zbuf  = scratch;                 // N x 4   (after mean2 dead)
    float* rbuf  = scratch + (size_t)NN * 4;

    const int* e_src = ei;
    const int* e_dst = ei + EE;

    hipMemsetAsync(deg, 0, (size_t)NN * 4, stream);
    hipMemsetAsync(cursor, 0, (size_t)NN * 4, stream);

    k_deg<<<(EE + 255) / 256, 256, 0, stream>>>(e_dst, deg);
    k_bsum<<<NB, 256, 0, stream>>>(deg, bsum);
    k_bscan<<<1, 512, 0, stream>>>(bsum, boff, row_start);
    k_scan2<<<NB, 256, 0, stream>>>(deg, boff, row_start, deg_inv);
    k_fill<<<(EE + 255) / 256, 256, 0, stream>>>(e_src, e_dst, row_start, cursor, csr_src);

    // layer 1: 40 -> 64  (mean: 10 lanes/node exact; lin: 20.8KB LDS -> 7 blocks/CU)
    k_mean8<40, 10><<<((size_t)NN * 10 + 255) / 256, 256, 0, stream>>>(x, row_start, csr_src, deg_inv, mean1);
    k_lin4<40, 64, true><<<dim3(1792, 1), 256, 0, stream>>>(mean1, x, W1l, b1, W1r, h1);

    // layer 2: 64 -> 128  (lin: 33.3KB LDS -> 4 blocks/CU)
    k_mean8<64, 16><<<((size_t)NN * 16 + 255) / 256, 256, 0, stream>>>(h1, row_start, csr_src, deg_inv, mean2);
    k_lin4<64, 128, true><<<dim3(1024, 2), 256, 0, stream>>>(mean2, h1, W2l, b2, W2r, h2);

    // layer 3: 128 -> 3, transform-before-gather (z/r padded to float4 rows)
    k_zr<<<((size_t)NN * 64 + 255) / 256, 256, 0, stream>>>(h2, W4l, W4r, zbuf, rbuf);
    k_final<<<(NN + 255) / 256, 256, 0, stream>>>(zbuf, rbuf, b4, row_start, csr_src, deg_inv, out);
}

// Round 5
// 425.003 us; speedup vs baseline: 1.7154x; 1.6414x over previous
//
#include <hip/hip_runtime.h>
#include <hip/hip_bf16.h>

// GraphSAGE 3-layer: 40 -> 64 -> 128 -> 3, mean aggregation over fixed edges.
// R5: replace VALU-GEMV k_lin (208us, 8x over both VALU and memory floors)
// with MFMA bf16 GEMM over concatenated A=[mean|root]; bf16 storage halves
// gather traffic. fp32 accumulation throughout (gather + MFMA acc).

static constexpr int NN = 100000;
static constexpr int EE = 1600000;
static constexpr int NB = (NN + 255) / 256;   // 391 scan blocks

typedef __attribute__((ext_vector_type(8))) short short8;
typedef __attribute__((ext_vector_type(4))) float f32x4;

__device__ __forceinline__ float bf2f(unsigned short u) {
    union { unsigned int i; float f; } c; c.i = ((unsigned int)u) << 16; return c.f;
}
__device__ __forceinline__ unsigned short f2bf(float f) {
    union { float f; unsigned int i; } c; c.f = f;
    unsigned int x = c.i;
    return (unsigned short)((x + 0x7fffu + ((x >> 16) & 1u)) >> 16);   // RNE
}

// ---------------- degree histogram ----------------
__global__ __launch_bounds__(256) void k_deg(const int* __restrict__ dst, int* __restrict__ deg) {
    int e = blockIdx.x * 256 + threadIdx.x;
    if (e < EE) atomicAdd(&deg[dst[e]], 1);
}

// ---------------- hierarchical scan: block sums ----------------
__global__ __launch_bounds__(256) void k_bsum(const int* __restrict__ deg, int* __restrict__ bsum) {
    int i = blockIdx.x * 256 + threadIdx.x;
    int v = (i < NN) ? deg[i] : 0;
    int lane = threadIdx.x & 63, wid = threadIdx.x >> 6;
#pragma unroll
    for (int d = 32; d; d >>= 1) v += __shfl_down(v, d, 64);
    __shared__ int wsum[4];
    if (lane == 0) wsum[wid] = v;
    __syncthreads();
    if (threadIdx.x == 0) bsum[blockIdx.x] = wsum[0] + wsum[1] + wsum[2] + wsum[3];
}

// ---------------- scan of 391 block sums (one block) ----------------
__global__ __launch_bounds__(512) void k_bscan(const int* __restrict__ bsum, int* __restrict__ boff,
                                               int* __restrict__ row_start) {
    __shared__ int s[512];
    int tid = threadIdx.x;
    int v = (tid < NB) ? bsum[tid] : 0;
    s[tid] = v;
    __syncthreads();
    for (int d = 1; d < 512; d <<= 1) {
        int t = (tid >= d) ? s[tid - d] : 0;
        __syncthreads();
        s[tid] += t;
        __syncthreads();
    }
    if (tid < NB) boff[tid] = s[tid] - v;   // exclusive
    if (tid == 0) row_start[NN] = EE;
}

// ---------------- final scan: row_start + deg_inv ----------------
__global__ __launch_bounds__(256) void k_scan2(const int* __restrict__ deg, const int* __restrict__ boff,
                                               int* __restrict__ row_start, float* __restrict__ deg_inv) {
    int tid = threadIdx.x, lane = tid & 63, wid = tid >> 6;
    int i = blockIdx.x * 256 + tid;
    int v = (i < NN) ? deg[i] : 0;
    int inc = v;
#pragma unroll
    for (int d = 1; d < 64; d <<= 1) {
        int t = __shfl_up(inc, d, 64);
        if (lane >= d) inc += t;
    }
    __shared__ int wsum[4];
    if (lane == 63) wsum[wid] = inc;
    __syncthreads();
    if (tid == 0) {
        int s = 0;
#pragma unroll
        for (int j = 0; j < 4; ++j) { int t = wsum[j]; wsum[j] = s; s += t; }
    }
    __syncthreads();
    if (i < NN) {
        row_start[i] = boff[blockIdx.x] + wsum[wid] + (inc - v);
        deg_inv[i] = (v > 0) ? 1.0f / (float)v : 0.0f;
    }
}

// ---------------- CSR scatter ----------------
__global__ __launch_bounds__(256) void k_fill(const int* __restrict__ src, const int* __restrict__ dst,
                                              const int* __restrict__ row_start, int* __restrict__ cursor,
                                              int* __restrict__ csr_src) {
    int e = blockIdx.x * 256 + threadIdx.x;
    if (e < EE) {
        int d = dst[e];
        int pos = atomicAdd(&cursor[d], 1);
        csr_src[row_start[d] + pos] = src[e];
    }
}

// ---------------- fp32 -> bf16 row convert (x: N x 40) ----------------
__global__ __launch_bounds__(256) void k_cvt(const float* __restrict__ x, unsigned short* __restrict__ xb) {
    int i = blockIdx.x * 256 + threadIdx.x;            // groups of 8 elems
    if (i >= NN * 40 / 8) return;
    const float4* p = (const float4*)(x + (size_t)i * 8);
    float4 a = p[0], b = p[1];
    short8 v;
    v[0] = (short)f2bf(a.x); v[1] = (short)f2bf(a.y); v[2] = (short)f2bf(a.z); v[3] = (short)f2bf(a.w);
    v[4] = (short)f2bf(b.x); v[5] = (short)f2bf(b.y); v[6] = (short)f2bf(b.z); v[7] = (short)f2bf(b.w);
    *(short8*)(xb + (size_t)i * 8) = v;
}

// ---------------- bf16 mean-aggregate into concat A = [mean(FinP) | root(FinP)] ----------------
// 8 lanes/node, 8 bf16 (16B) per lane. fp32 accumulation. Also writes pad
// columns (zeros) and copies the root row, so A is fully initialized.
template<int Fin, int FinP>
__global__ __launch_bounds__(256) void k_meanb(const unsigned short* __restrict__ xin,
                                               const int* __restrict__ row_start,
                                               const int* __restrict__ csr_src,
                                               const float* __restrict__ deg_inv,
                                               unsigned short* __restrict__ Acat) {
    constexpr int CH = Fin / 8;     // data chunks (5 or 8)
    constexpr int PCH = FinP / 8;   // padded chunks (6 or 8)
    constexpr int K2 = 2 * FinP;
    int gid = blockIdx.x * 256 + threadIdx.x;
    int node = gid >> 3;
    int c = gid & 7;
    if (node >= NN) return;
    float acc[8] = {0, 0, 0, 0, 0, 0, 0, 0};
    if (c < CH) {
        const unsigned short* xq = xin + c * 8;
        int rs = row_start[node], re = row_start[node + 1];
        int k = rs;
        for (; k + 4 <= re; k += 4) {
            int s0 = csr_src[k], s1 = csr_src[k + 1], s2 = csr_src[k + 2], s3 = csr_src[k + 3];
            short8 v0 = *(const short8*)(xq + (size_t)s0 * Fin);
            short8 v1 = *(const short8*)(xq + (size_t)s1 * Fin);
            short8 v2 = *(const short8*)(xq + (size_t)s2 * Fin);
            short8 v3 = *(const short8*)(xq + (size_t)s3 * Fin);
#pragma unroll
            for (int j = 0; j < 8; ++j)
                acc[j] += (bf2f((unsigned short)v0[j]) + bf2f((unsigned short)v1[j]))
                        + (bf2f((unsigned short)v2[j]) + bf2f((unsigned short)v3[j]));
        }
        for (; k < re; ++k) {
            short8 v0 = *(const short8*)(xq + (size_t)csr_src[k] * Fin);
#pragma unroll
            for (int j = 0; j < 8; ++j) acc[j] += bf2f((unsigned short)v0[j]);
        }
        float di = deg_inv[node];
#pragma unroll
        for (int j = 0; j < 8; ++j) acc[j] *= di;
    }
    if (c < PCH) {
        short8 m;
#pragma unroll
        for (int j = 0; j < 8; ++j) m[j] = (c < CH) ? (short)f2bf(acc[j]) : (short)0;
        *(short8*)(Acat + (size_t)node * K2 + c * 8) = m;
        short8 rv;
        if (c < CH) {
            rv = *(const short8*)(xin + (size_t)node * Fin + c * 8);
        } else {
#pragma unroll
            for (int j = 0; j < 8; ++j) rv[j] = 0;
        }
        *(short8*)(Acat + (size_t)node * K2 + FinP + c * 8) = rv;
    }
}

// ---------------- MFMA GEMM: out = relu?(A @ [Wl;Wr]^T + b), A = N x 2FinP bf16 ----------------
// B staged fragment-major in LDS (lane-contiguous 16B -> conflict-free b128).
// 32 nodes (2 m-tiles) per wave iteration; fp32 accumulators (AGPR/VGPR).
template<int Fin, int FinP, int Fout, bool RELU>
__global__ __launch_bounds__(256) void k_gemm(const unsigned short* __restrict__ A,
                                              const float* __restrict__ Wl,
                                              const float* __restrict__ bias,
                                              const float* __restrict__ Wr,
                                              unsigned short* __restrict__ out) {
    constexpr int K = 2 * FinP;
    constexpr int KS = K / 32;
    constexpr int TILES = Fout / 16;
    __shared__ short sB[TILES * KS * 64 * 8];
    const int lane = threadIdx.x & 63;
    // stage B fragments: frag(t,ks,lane)[j] = B[k=ks*32+(lane>>4)*8+j][o=t*16+(lane&15)]
    for (int idx = threadIdx.x; idx < TILES * KS * 64; idx += 256) {
        int l = idx & 63;
        int ks = (idx >> 6) % KS;
        int t = idx / (64 * KS);
        int o = t * 16 + (l & 15);
        int kbase = ks * 32 + (l >> 4) * 8;
        short8 v;
#pragma unroll
        for (int j = 0; j < 8; ++j) {
            int k = kbase + j;
            float w;
            if (k < FinP) w = (k < Fin) ? Wl[(size_t)o * Fin + k] : 0.f;
            else { int k2 = k - FinP; w = (k2 < Fin) ? Wr[(size_t)o * Fin + k2] : 0.f; }
            v[j] = (short)f2bf(w);
        }
        *(short8*)&sB[idx * 8] = v;
    }
    __syncthreads();
    float bias_t[TILES];
#pragma unroll
    for (int t = 0; t < TILES; ++t) bias_t[t] = bias[t * 16 + (lane & 15)];

    const int wave = blockIdx.x * 4 + (threadIdx.x >> 6);
    const int nchunks = NN / 32;                        // 3125
    for (int ci = wave; ci < nchunks; ci += gridDim.x * 4) {
        int nbase = ci * 32;
        const unsigned short* a0 = A + (size_t)(nbase + (lane & 15)) * K + (lane >> 4) * 8;
        short8 af[2][KS];
#pragma unroll
        for (int ks = 0; ks < KS; ++ks) {
            af[0][ks] = *(const short8*)(a0 + ks * 32);
            af[1][ks] = *(const short8*)(a0 + 16 * K + ks * 32);
        }
        f32x4 acc[2][TILES];
#pragma unroll
        for (int m = 0; m < 2; ++m)
#pragma unroll
            for (int t = 0; t < TILES; ++t) acc[m][t] = (f32x4){0.f, 0.f, 0.f, 0.f};
#pragma unroll
        for (int t = 0; t < TILES; ++t)
#pragma unroll
            for (int ks = 0; ks < KS; ++ks) {
                short8 bf = *(const short8*)&sB[((t * KS + ks) * 64 + lane) * 8];
                acc[0][t] = __builtin_amdgcn_mfma_f32_16x16x32_bf16(af[0][ks], bf, acc[0][t], 0, 0, 0);
                acc[1][t] = __builtin_amdgcn_mfma_f32_16x16x32_bf16(af[1][ks], bf, acc[1][t], 0, 0, 0);
            }
        // epilogue: D row = (lane>>4)*4 + r (node), col = lane&15 (out feature)
#pragma unroll
        for (int m = 0; m < 2; ++m) {
            int nrow = nbase + m * 16 + (lane >> 4) * 4;
#pragma unroll
            for (int t = 0; t < TILES; ++t) {
                int col = t * 16 + (lane & 15);
#pragma unroll
                for (int r = 0; r < 4; ++r) {
                    float v = acc[m][t][r] + bias_t[t];
                    if (RELU) v = fmaxf(v, 0.f);
                    out[(size_t)(nrow + r) * Fout + col] = f2bf(v);
                }
            }
        }
    }
}

// ---------------- layer 3 transforms: z = h2@W4l.T, r = h2@W4r.T (h2 bf16) ----------------
__global__ __launch_bounds__(256) void k_zr(const unsigned short* __restrict__ h2,
                                            const float* __restrict__ W4l, const float* __restrict__ W4r,
                                            float* __restrict__ z, float* __restrict__ r) {
    int node = (blockIdx.x * 256 + threadIdx.x) >> 6;
    int lane = threadIdx.x & 63;
    if (node >= NN) return;
    float h0 = bf2f(h2[(size_t)node * 128 + lane]);
    float h1v = bf2f(h2[(size_t)node * 128 + 64 + lane]);
    float zc0 = h0 * W4l[0 * 128 + lane] + h1v * W4l[0 * 128 + 64 + lane];
    float zc1 = h0 * W4l[1 * 128 + lane] + h1v * W4l[1 * 128 + 64 + lane];
    float zc2 = h0 * W4l[2 * 128 + lane] + h1v * W4l[2 * 128 + 64 + lane];
    float rc0 = h0 * W4r[0 * 128 + lane] + h1v * W4r[0 * 128 + 64 + lane];
    float rc1 = h0 * W4r[1 * 128 + lane] + h1v * W4r[1 * 128 + 64 + lane];
    float rc2 = h0 * W4r[2 * 128 + lane] + h1v * W4r[2 * 128 + 64 + lane];
#pragma unroll
    for (int d = 32; d; d >>= 1) {
        zc0 += __shfl_down(zc0, d, 64); zc1 += __shfl_down(zc1, d, 64); zc2 += __shfl_down(zc2, d, 64);
        rc0 += __shfl_down(rc0, d, 64); rc1 += __shfl_down(rc1, d, 64); rc2 += __shfl_down(rc2, d, 64);
    }
    if (lane == 0) {
        *(float4*)&z[(size_t)node * 4] = make_float4(zc0, zc1, zc2, 0.f);
        *(float4*)&r[(size_t)node * 4] = make_float4(rc0, rc1, rc2, 0.f);
    }
}

// ---------------- final: out = mean(z)[n] + r[n] + b4 ----------------
__global__ __launch_bounds__(256) void k_final(const float* __restrict__ z, const float* __restrict__ r,
                                               const float* __restrict__ b4,
                                               const int* __restrict__ row_start, const int* __restrict__ csr_src,
                                               const float* __restrict__ deg_inv, float* __restrict__ out) {
    int n = blockIdx.x * 256 + threadIdx.x;
    if (n >= NN) return;
    int rs = row_start[n], re = row_start[n + 1];
    float a0 = 0, a1 = 0, a2 = 0, b0 = 0, b1 = 0, b2 = 0;
    int k = rs;
    for (; k + 4 <= re; k += 4) {
        int s0 = csr_src[k], s1 = csr_src[k + 1], s2 = csr_src[k + 2], s3 = csr_src[k + 3];
        float4 z0 = *(const float4*)&z[4 * (size_t)s0];
        float4 z1 = *(const float4*)&z[4 * (size_t)s1];
        float4 z2 = *(const float4*)&z[4 * (size_t)s2];
        float4 z3 = *(const float4*)&z[4 * (size_t)s3];
        a0 += z0.x; a1 += z0.y; a2 += z0.z;
        b0 += z1.x; b1 += z1.y; b2 += z1.z;
        a0 += z2.x; a1 += z2.y; a2 += z2.z;
        b0 += z3.x; b1 += z3.y; b2 += z3.z;
    }
    for (; k < re; ++k) {
        float4 z0 = *(const float4*)&z[4 * (size_t)csr_src[k]];
        a0 += z0.x; a1 += z0.y; a2 += z0.z;
    }
    float di = deg_inv[n];
    float4 rn = *(const float4*)&r[4 * (size_t)n];
    out[(size_t)n * 3 + 0] = (a0 + b0) * di + rn.x + b4[0];
    out[(size_t)n * 3 + 1] = (a1 + b1) * di + rn.y + b4[1];
    out[(size_t)n * 3 + 2] = (a2 + b2) * di + rn.z + b4[2];
}

extern "C" void kernel_launch(void* const* d_in, const int* in_sizes, int n_in,
                              void* d_out, int out_size, void* d_ws, size_t ws_size,
                              hipStream_t stream) {
    const float* x   = (const float*)d_in[0];
    const int*   ei  = (const int*)d_in[1];
    const float* W1l = (const float*)d_in[2];
    const float* b1  = (const float*)d_in[3];
    const float* W1r = (const float*)d_in[4];
    const float* W2l = (const float*)d_in[5];
    const float* b2  = (const float*)d_in[6];
    const float* W2r = (const float*)d_in[7];
    const float* W4l = (const float*)d_in[8];
    const float* b4  = (const float*)d_in[9];
    const float* W4r = (const float*)d_in[10];
    float* out = (float*)d_out;

    char* ws = (char*)d_ws;
    size_t off = 0;
    auto alloc = [&](size_t bytes) -> void* {
        void* p = ws + off;
        off = (off + bytes + 255) & ~(size_t)255;
        return p;
    };
    int*   deg       = (int*)alloc((size_t)NN * 4);
    int*   row_start = (int*)alloc(((size_t)NN + 1) * 4);
    int*   cursor    = (int*)alloc((size_t)NN * 4);
    int*   csr_src   = (int*)alloc((size_t)EE * 4);
    float* deg_inv   = (float*)alloc((size_t)NN * 4);
    int*   bsum      = (int*)alloc((size_t)NB * 4);
    int*   boff      = (int*)alloc((size_t)NB * 4);
    unsigned short* xb    = (unsigned short*)alloc((size_t)NN * 40 * 2);   // x bf16
    unsigned short* A1cat = (unsigned short*)alloc((size_t)NN * 96 * 2);   // [mean40+pad8 | x40+pad8]
    unsigned short* h1    = (unsigned short*)alloc((size_t)NN * 64 * 2);   // layer-1 out bf16
    unsigned short* A2cat = (unsigned short*)alloc((size_t)NN * 128 * 2);  // [mean64 | h1]
    unsigned short* h2    = (unsigned short*)alloc((size_t)NN * 128 * 2);  // layer-2 out bf16
    float* zbuf = (float*)alloc((size_t)NN * 4 * 4);
    float* rbuf = (float*)alloc((size_t)NN * 4 * 4);

    const int* e_src = ei;
    const int* e_dst = ei + EE;

    hipMemsetAsync(deg, 0, (size_t)NN * 4, stream);
    hipMemsetAsync(cursor, 0, (size_t)NN * 4, stream);

    k_deg<<<(EE + 255) / 256, 256, 0, stream>>>(e_dst, deg);
    k_cvt<<<((NN * 40 / 8) + 255) / 256, 256, 0, stream>>>(x, xb);   // independent of CSR
    k_bsum<<<NB, 256, 0, stream>>>(deg, bsum);
    k_bscan<<<1, 512, 0, stream>>>(bsum, boff, row_start);
    k_scan2<<<NB, 256, 0, stream>>>(deg, boff, row_start, deg_inv);
    k_fill<<<(EE + 255) / 256, 256, 0, stream>>>(e_src, e_dst, row_start, cursor, csr_src);

    const int mean_blocks = ((size_t)NN * 8 + 255) / 256;   // 3125
    const int gemm_blocks = 782;                            // 3128 waves ~ 3125 chunks

    // layer 1: 40 -> 64  (K = 2*48 = 96)
    k_meanb<40, 48><<<mean_blocks, 256, 0, stream>>>(xb, row_start, csr_src, deg_inv, A1cat);
    k_gemm<40, 48, 64, true><<<gemm_blocks, 256, 0, stream>>>(A1cat, W1l, b1, W1r, h1);

    // layer 2: 64 -> 128  (K = 128)
    k_meanb<64, 64><<<mean_blocks, 256, 0, stream>>>(h1, row_start, csr_src, deg_inv, A2cat);
    k_gemm<64, 64, 128, true><<<gemm_blocks, 256, 0, stream>>>(A2cat, W2l, b2, W2r, h2);

    // layer 3: 128 -> 3, transform-before-gather
    k_zr<<<((size_t)NN * 64 + 255) / 256, 256, 0, stream>>>(h2, W4l, W4r, zbuf, rbuf);
    k_final<<<(NN + 255) / 256, 256, 0, stream>>>(zbuf, rbuf, b4, row_start, csr_src, deg_inv, out);
}

// Round 6
// 393.477 us; speedup vs baseline: 1.8529x; 1.0801x over previous
//
#include <hip/hip_runtime.h>
#include <hip/hip_bf16.h>

// GraphSAGE 3-layer: 40 -> 64 -> 128 -> 3, mean aggregation over fixed edges.
// R6: k_fill rewrote 107MB to HBM (partial-line writebacks: csr lines dirtied
// from all 8 non-coherent XCD L2s). Now XCD-partitioned scatter: partition
// dst range 8 ways, partition = blockIdx%8 (round-robin XCD heuristic), so
// each csr line is written by one XCD only. Rest unchanged from R5.

static constexpr int NN = 100000;
static constexpr int EE = 1600000;
static constexpr int NB = (NN + 255) / 256;   // 391 scan blocks
static constexpr int NPART = 8;
static constexpr int PSIZE = (NN + NPART - 1) / NPART;   // 12500

typedef __attribute__((ext_vector_type(8))) short short8;
typedef __attribute__((ext_vector_type(4))) float f32x4;

__device__ __forceinline__ float bf2f(unsigned short u) {
    union { unsigned int i; float f; } c; c.i = ((unsigned int)u) << 16; return c.f;
}
__device__ __forceinline__ unsigned short f2bf(float f) {
    union { float f; unsigned int i; } c; c.f = f;
    unsigned int x = c.i;
    return (unsigned short)((x + 0x7fffu + ((x >> 16) & 1u)) >> 16);   // RNE
}

// ---------------- degree histogram ----------------
__global__ __launch_bounds__(256) void k_deg(const int* __restrict__ dst, int* __restrict__ deg) {
    int e = blockIdx.x * 256 + threadIdx.x;
    if (e < EE) atomicAdd(&deg[dst[e]], 1);
}

// ---------------- hierarchical scan: block sums ----------------
__global__ __launch_bounds__(256) void k_bsum(const int* __restrict__ deg, int* __restrict__ bsum) {
    int i = blockIdx.x * 256 + threadIdx.x;
    int v = (i < NN) ? deg[i] : 0;
    int lane = threadIdx.x & 63, wid = threadIdx.x >> 6;
#pragma unroll
    for (int d = 32; d; d >>= 1) v += __shfl_down(v, d, 64);
    __shared__ int wsum[4];
    if (lane == 0) wsum[wid] = v;
    __syncthreads();
    if (threadIdx.x == 0) bsum[blockIdx.x] = wsum[0] + wsum[1] + wsum[2] + wsum[3];
}

// ---------------- scan of 391 block sums (one block) ----------------
__global__ __launch_bounds__(512) void k_bscan(const int* __restrict__ bsum, int* __restrict__ boff,
                                               int* __restrict__ row_start) {
    __shared__ int s[512];
    int tid = threadIdx.x;
    int v = (tid < NB) ? bsum[tid] : 0;
    s[tid] = v;
    __syncthreads();
    for (int d = 1; d < 512; d <<= 1) {
        int t = (tid >= d) ? s[tid - d] : 0;
        __syncthreads();
        s[tid] += t;
        __syncthreads();
    }
    if (tid < NB) boff[tid] = s[tid] - v;   // exclusive
    if (tid == 0) row_start[NN] = EE;
}

// ---------------- final scan: row_start + deg_inv ----------------
__global__ __launch_bounds__(256) void k_scan2(const int* __restrict__ deg, const int* __restrict__ boff,
                                               int* __restrict__ row_start, float* __restrict__ deg_inv) {
    int tid = threadIdx.x, lane = tid & 63, wid = tid >> 6;
    int i = blockIdx.x * 256 + tid;
    int v = (i < NN) ? deg[i] : 0;
    int inc = v;
#pragma unroll
    for (int d = 1; d < 64; d <<= 1) {
        int t = __shfl_up(inc, d, 64);
        if (lane >= d) inc += t;
    }
    __shared__ int wsum[4];
    if (lane == 63) wsum[wid] = inc;
    __syncthreads();
    if (tid == 0) {
        int s = 0;
#pragma unroll
        for (int j = 0; j < 4; ++j) { int t = wsum[j]; wsum[j] = s; s += t; }
    }
    __syncthreads();
    if (i < NN) {
        row_start[i] = boff[blockIdx.x] + wsum[wid] + (inc - v);
        deg_inv[i] = (v > 0) ? 1.0f / (float)v : 0.0f;
    }
}

// ---------------- CSR scatter, XCD-partitioned by dst range ----------------
// partition = blockIdx%8 matches the round-robin block->XCD dispatch, so all
// writes to a given csr_src line come from one XCD's L2 (full-line writeback
// once, not 8 partial writebacks). Each partition scans the whole dst list
// (LLC-resident after first pass).
__global__ __launch_bounds__(256) void k_fill_part(const int* __restrict__ src, const int* __restrict__ dst,
                                                   const int* __restrict__ row_start, int* __restrict__ cursor,
                                                   int* __restrict__ csr_src, int blocks_per_part) {
    const int part = blockIdx.x & (NPART - 1);
    const int bp = blockIdx.x >> 3;
    const int lo = part * PSIZE;
    const int hi = (lo + PSIZE < NN) ? lo + PSIZE : NN;
    const int chunk = (EE + blocks_per_part - 1) / blocks_per_part;
    const int e0 = bp * chunk;
    const int e1 = (e0 + chunk < EE) ? e0 + chunk : EE;
    for (int e = e0 + threadIdx.x; e < e1; e += 256) {
        int d = dst[e];
        if (d >= lo && d < hi) {
            int pos = atomicAdd(&cursor[d], 1);
            csr_src[row_start[d] + pos] = src[e];
        }
    }
}

// ---------------- fp32 -> bf16 row convert (x: N x 40) ----------------
__global__ __launch_bounds__(256) void k_cvt(const float* __restrict__ x, unsigned short* __restrict__ xb) {
    int i = blockIdx.x * 256 + threadIdx.x;            // groups of 8 elems
    if (i >= NN * 40 / 8) return;
    const float4* p = (const float4*)(x + (size_t)i * 8);
    float4 a = p[0], b = p[1];
    short8 v;
    v[0] = (short)f2bf(a.x); v[1] = (short)f2bf(a.y); v[2] = (short)f2bf(a.z); v[3] = (short)f2bf(a.w);
    v[4] = (short)f2bf(b.x); v[5] = (short)f2bf(b.y); v[6] = (short)f2bf(b.z); v[7] = (short)f2bf(b.w);
    *(short8*)(xb + (size_t)i * 8) = v;
}

// ---------------- bf16 mean-aggregate into concat A = [mean(FinP) | root(FinP)] ----------------
template<int Fin, int FinP>
__global__ __launch_bounds__(256) void k_meanb(const unsigned short* __restrict__ xin,
                                               const int* __restrict__ row_start,
                                               const int* __restrict__ csr_src,
                                               const float* __restrict__ deg_inv,
                                               unsigned short* __restrict__ Acat) {
    constexpr int CH = Fin / 8;     // data chunks (5 or 8)
    constexpr int PCH = FinP / 8;   // padded chunks (6 or 8)
    constexpr int K2 = 2 * FinP;
    int gid = blockIdx.x * 256 + threadIdx.x;
    int node = gid >> 3;
    int c = gid & 7;
    if (node >= NN) return;
    float acc[8] = {0, 0, 0, 0, 0, 0, 0, 0};
    if (c < CH) {
        const unsigned short* xq = xin + c * 8;
        int rs = row_start[node], re = row_start[node + 1];
        int k = rs;
        for (; k + 4 <= re; k += 4) {
            int s0 = csr_src[k], s1 = csr_src[k + 1], s2 = csr_src[k + 2], s3 = csr_src[k + 3];
            short8 v0 = *(const short8*)(xq + (size_t)s0 * Fin);
            short8 v1 = *(const short8*)(xq + (size_t)s1 * Fin);
            short8 v2 = *(const short8*)(xq + (size_t)s2 * Fin);
            short8 v3 = *(const short8*)(xq + (size_t)s3 * Fin);
#pragma unroll
            for (int j = 0; j < 8; ++j)
                acc[j] += (bf2f((unsigned short)v0[j]) + bf2f((unsigned short)v1[j]))
                        + (bf2f((unsigned short)v2[j]) + bf2f((unsigned short)v3[j]));
        }
        for (; k < re; ++k) {
            short8 v0 = *(const short8*)(xq + (size_t)csr_src[k] * Fin);
#pragma unroll
            for (int j = 0; j < 8; ++j) acc[j] += bf2f((unsigned short)v0[j]);
        }
        float di = deg_inv[node];
#pragma unroll
        for (int j = 0; j < 8; ++j) acc[j] *= di;
    }
    if (c < PCH) {
        short8 m;
#pragma unroll
        for (int j = 0; j < 8; ++j) m[j] = (c < CH) ? (short)f2bf(acc[j]) : (short)0;
        *(short8*)(Acat + (size_t)node * K2 + c * 8) = m;
        short8 rv;
        if (c < CH) {
            rv = *(const short8*)(xin + (size_t)node * Fin + c * 8);
        } else {
#pragma unroll
            for (int j = 0; j < 8; ++j) rv[j] = 0;
        }
        *(short8*)(Acat + (size_t)node * K2 + FinP + c * 8) = rv;
    }
}

// ---------------- MFMA GEMM: out = relu?(A @ [Wl;Wr]^T + b), A = N x 2FinP bf16 ----------------
template<int Fin, int FinP, int Fout, bool RELU>
__global__ __launch_bounds__(256) void k_gemm(const unsigned short* __restrict__ A,
                                              const float* __restrict__ Wl,
                                              const float* __restrict__ bias,
                                              const float* __restrict__ Wr,
                                              unsigned short* __restrict__ out) {
    constexpr int K = 2 * FinP;
    constexpr int KS = K / 32;
    constexpr int TILES = Fout / 16;
    __shared__ short sB[TILES * KS * 64 * 8];
    const int lane = threadIdx.x & 63;
    for (int idx = threadIdx.x; idx < TILES * KS * 64; idx += 256) {
        int l = idx & 63;
        int ks = (idx >> 6) % KS;
        int t = idx / (64 * KS);
        int o = t * 16 + (l & 15);
        int kbase = ks * 32 + (l >> 4) * 8;
        short8 v;
#pragma unroll
        for (int j = 0; j < 8; ++j) {
            int k = kbase + j;
            float w;
            if (k < FinP) w = (k < Fin) ? Wl[(size_t)o * Fin + k] : 0.f;
            else { int k2 = k - FinP; w = (k2 < Fin) ? Wr[(size_t)o * Fin + k2] : 0.f; }
            v[j] = (short)f2bf(w);
        }
        *(short8*)&sB[idx * 8] = v;
    }
    __syncthreads();
    float bias_t[TILES];
#pragma unroll
    for (int t = 0; t < TILES; ++t) bias_t[t] = bias[t * 16 + (lane & 15)];

    const int wave = blockIdx.x * 4 + (threadIdx.x >> 6);
    const int nchunks = NN / 32;                        // 3125
    for (int ci = wave; ci < nchunks; ci += gridDim.x * 4) {
        int nbase = ci * 32;
        const unsigned short* a0 = A + (size_t)(nbase + (lane & 15)) * K + (lane >> 4) * 8;
        short8 af[2][KS];
#pragma unroll
        for (int ks = 0; ks < KS; ++ks) {
            af[0][ks] = *(const short8*)(a0 + ks * 32);
            af[1][ks] = *(const short8*)(a0 + 16 * K + ks * 32);
        }
        f32x4 acc[2][TILES];
#pragma unroll
        for (int m = 0; m < 2; ++m)
#pragma unroll
            for (int t = 0; t < TILES; ++t) acc[m][t] = (f32x4){0.f, 0.f, 0.f, 0.f};
#pragma unroll
        for (int t = 0; t < TILES; ++t)
#pragma unroll
            for (int ks = 0; ks < KS; ++ks) {
                short8 bf = *(const short8*)&sB[((t * KS + ks) * 64 + lane) * 8];
                acc[0][t] = __builtin_amdgcn_mfma_f32_16x16x32_bf16(af[0][ks], bf, acc[0][t], 0, 0, 0);
                acc[1][t] = __builtin_amdgcn_mfma_f32_16x16x32_bf16(af[1][ks], bf, acc[1][t], 0, 0, 0);
            }
#pragma unroll
        for (int m = 0; m < 2; ++m) {
            int nrow = nbase + m * 16 + (lane >> 4) * 4;
#pragma unroll
            for (int t = 0; t < TILES; ++t) {
                int col = t * 16 + (lane & 15);
#pragma unroll
                for (int r = 0; r < 4; ++r) {
                    float v = acc[m][t][r] + bias_t[t];
                    if (RELU) v = fmaxf(v, 0.f);
                    out[(size_t)(nrow + r) * Fout + col] = f2bf(v);
                }
            }
        }
    }
}

// ---------------- layer 3 transforms: z = h2@W4l.T, r = h2@W4r.T (h2 bf16) ----------------
__global__ __launch_bounds__(256) void k_zr(const unsigned short* __restrict__ h2,
                                            const float* __restrict__ W4l, const float* __restrict__ W4r,
                                            float* __restrict__ z, float* __restrict__ r) {
    int node = (blockIdx.x * 256 + threadIdx.x) >> 6;
    int lane = threadIdx.x & 63;
    if (node >= NN) return;
    float h0 = bf2f(h2[(size_t)node * 128 + lane]);
    float h1v = bf2f(h2[(size_t)node * 128 + 64 + lane]);
    float zc0 = h0 * W4l[0 * 128 + lane] + h1v * W4l[0 * 128 + 64 + lane];
    float zc1 = h0 * W4l[1 * 128 + lane] + h1v * W4l[1 * 128 + 64 + lane];
    float zc2 = h0 * W4l[2 * 128 + lane] + h1v * W4l[2 * 128 + 64 + lane];
    float rc0 = h0 * W4r[0 * 128 + lane] + h1v * W4r[0 * 128 + 64 + lane];
    float rc1 = h0 * W4r[1 * 128 + lane] + h1v * W4r[1 * 128 + 64 + lane];
    float rc2 = h0 * W4r[2 * 128 + lane] + h1v * W4r[2 * 128 + 64 + lane];
#pragma unroll
    for (int d = 32; d; d >>= 1) {
        zc0 += __shfl_down(zc0, d, 64); zc1 += __shfl_down(zc1, d, 64); zc2 += __shfl_down(zc2, d, 64);
        rc0 += __shfl_down(rc0, d, 64); rc1 += __shfl_down(rc1, d, 64); rc2 += __shfl_down(rc2, d, 64);
    }
    if (lane == 0) {
        *(float4*)&z[(size_t)node * 4] = make_float4(zc0, zc1, zc2, 0.f);
        *(float4*)&r[(size_t)node * 4] = make_float4(rc0, rc1, rc2, 0.f);
    }
}

// ---------------- final: out = mean(z)[n] + r[n] + b4 ----------------
__global__ __launch_bounds__(256) void k_final(const float* __restrict__ z, const float* __restrict__ r,
                                               const float* __restrict__ b4,
                                               const int* __restrict__ row_start, const int* __restrict__ csr_src,
                                               const float* __restrict__ deg_inv, float* __restrict__ out) {
    int n = blockIdx.x * 256 + threadIdx.x;
    if (n >= NN) return;
    int rs = row_start[n], re = row_start[n + 1];
    float a0 = 0, a1 = 0, a2 = 0, b0 = 0, b1 = 0, b2 = 0;
    int k = rs;
    for (; k + 4 <= re; k += 4) {
        int s0 = csr_src[k], s1 = csr_src[k + 1], s2 = csr_src[k + 2], s3 = csr_src[k + 3];
        float4 z0 = *(const float4*)&z[4 * (size_t)s0];
        float4 z1 = *(const float4*)&z[4 * (size_t)s1];
        float4 z2 = *(const float4*)&z[4 * (size_t)s2];
        float4 z3 = *(const float4*)&z[4 * (size_t)s3];
        a0 += z0.x; a1 += z0.y; a2 += z0.z;
        b0 += z1.x; b1 += z1.y; b2 += z1.z;
        a0 += z2.x; a1 += z2.y; a2 += z2.z;
        b0 += z3.x; b1 += z3.y; b2 += z3.z;
    }
    for (; k < re; ++k) {
        float4 z0 = *(const float4*)&z[4 * (size_t)csr_src[k]];
        a0 += z0.x; a1 += z0.y; a2 += z0.z;
    }
    float di = deg_inv[n];
    float4 rn = *(const float4*)&r[4 * (size_t)n];
    out[(size_t)n * 3 + 0] = (a0 + b0) * di + rn.x + b4[0];
    out[(size_t)n * 3 + 1] = (a1 + b1) * di + rn.y + b4[1];
    out[(size_t)n * 3 + 2] = (a2 + b2) * di + rn.z + b4[2];
}

extern "C" void kernel_launch(void* const* d_in, const int* in_sizes, int n_in,
                              void* d_out, int out_size, void* d_ws, size_t ws_size,
                              hipStream_t stream) {
    const float* x   = (const float*)d_in[0];
    const int*   ei  = (const int*)d_in[1];
    const float* W1l = (const float*)d_in[2];
    const float* b1  = (const float*)d_in[3];
    const float* W1r = (const float*)d_in[4];
    const float* W2l = (const float*)d_in[5];
    const float* b2  = (const float*)d_in[6];
    const float* W2r = (const float*)d_in[7];
    const float* W4l = (const float*)d_in[8];
    const float* b4  = (const float*)d_in[9];
    const float* W4r = (const float*)d_in[10];
    float* out = (float*)d_out;

    char* ws = (char*)d_ws;
    size_t off = 0;
    auto alloc = [&](size_t bytes) -> void* {
        void* p = ws + off;
        off = (off + bytes + 255) & ~(size_t)255;
        return p;
    };
    int*   deg       = (int*)alloc((size_t)NN * 4);
    int*   row_start = (int*)alloc(((size_t)NN + 1) * 4);
    int*   cursor    = (int*)alloc((size_t)NN * 4);
    int*   csr_src   = (int*)alloc((size_t)EE * 4);
    float* deg_inv   = (float*)alloc((size_t)NN * 4);
    int*   bsum      = (int*)alloc((size_t)NB * 4);
    int*   boff      = (int*)alloc((size_t)NB * 4);
    unsigned short* xb    = (unsigned short*)alloc((size_t)NN * 40 * 2);
    unsigned short* A1cat = (unsigned short*)alloc((size_t)NN * 96 * 2);
    unsigned short* h1    = (unsigned short*)alloc((size_t)NN * 64 * 2);
    unsigned short* A2cat = (unsigned short*)alloc((size_t)NN * 128 * 2);
    unsigned short* h2    = (unsigned short*)alloc((size_t)NN * 128 * 2);
    float* zbuf = (float*)alloc((size_t)NN * 4 * 4);
    float* rbuf = (float*)alloc((size_t)NN * 4 * 4);

    const int* e_src = ei;
    const int* e_dst = ei + EE;

    hipMemsetAsync(deg, 0, (size_t)NN * 4, stream);
    hipMemsetAsync(cursor, 0, (size_t)NN * 4, stream);

    k_deg<<<(EE + 255) / 256, 256, 0, stream>>>(e_dst, deg);
    k_cvt<<<((NN * 40 / 8) + 255) / 256, 256, 0, stream>>>(x, xb);
    k_bsum<<<NB, 256, 0, stream>>>(deg, bsum);
    k_bscan<<<1, 512, 0, stream>>>(bsum, boff, row_start);
    k_scan2<<<NB, 256, 0, stream>>>(deg, boff, row_start, deg_inv);

    const int blocks_per_part = 96;   // 768 blocks total; each scans E/96 edges
    k_fill_part<<<NPART * blocks_per_part, 256, 0, stream>>>(e_src, e_dst, row_start, cursor, csr_src, blocks_per_part);

    const int mean_blocks = ((size_t)NN * 8 + 255) / 256;   // 3125
    const int gemm_blocks = 782;

    // layer 1: 40 -> 64  (K = 2*48 = 96)
    k_meanb<40, 48><<<mean_blocks, 256, 0, stream>>>(xb, row_start, csr_src, deg_inv, A1cat);
    k_gemm<40, 48, 64, true><<<gemm_blocks, 256, 0, stream>>>(A1cat, W1l, b1, W1r, h1);

    // layer 2: 64 -> 128  (K = 128)
    k_meanb<64, 64><<<mean_blocks, 256, 0, stream>>>(h1, row_start, csr_src, deg_inv, A2cat);
    k_gemm<64, 64, 128, true><<<gemm_blocks, 256, 0, stream>>>(A2cat, W2l, b2, W2r, h2);

    // layer 3: 128 -> 3, transform-before-gather
    k_zr<<<((size_t)NN * 64 + 255) / 256, 256, 0, stream>>>(h2, W4l, W4r, zbuf, rbuf);
    k_final<<<(NN + 255) / 256, 256, 0, stream>>>(zbuf, rbuf, b4, row_start, csr_src, deg_inv, out);
}